// Round 14
// baseline (459.828 us; speedup 1.0000x reference)
//
#include <hip/hip_runtime.h>
#include <hip/hip_bf16.h>
#include <math.h>

#define NN 50000
#define NE 800000
#define NR 16
#define DD 64
#define OSTRIDE 192   // 3*D concat output stride
#define QSTRIDE 1032  // f16 elems per node row in q_lds (1024 + 8 pad)

typedef _Float16 f16;
typedef f16 f16x8 __attribute__((ext_vector_type(8)));
typedef f16 f16x4 __attribute__((ext_vector_type(4)));
typedef f16 f16x2 __attribute__((ext_vector_type(2)));
typedef __attribute__((ext_vector_type(4))) float f32x4;

__device__ inline float tanh_fast(float x) {
    return 1.f - 2.f / (__expf(2.f * x) + 1.f);
}

__device__ inline float dot2acc(f16x2 a, f16x2 b, float c) {
#if __has_builtin(__builtin_amdgcn_fdot2)
    return __builtin_amdgcn_fdot2(a, b, c, false);
#else
    return c + (float)a[0] * (float)b[0] + (float)a[1] * (float)b[1];
#endif
}

// ---------- CSR build ----------
__global__ void k_deg(const int* __restrict__ dst, int* __restrict__ cnt) {
    for (int e = blockIdx.x * blockDim.x + threadIdx.x; e < NE;
         e += gridDim.x * blockDim.x)
        atomicAdd(&cnt[dst[e]], 1);
}

__global__ __launch_bounds__(256) void k_scan1(const int* __restrict__ cnt,
                                               int* __restrict__ rowptr,
                                               int* __restrict__ bsum) {
    __shared__ int sh[256];
    int b = blockIdx.x, t = threadIdx.x;
    int i = b * 256 + t;
    int v = (i < NN) ? cnt[i] : 0;
    sh[t] = v;
    __syncthreads();
    #pragma unroll
    for (int o = 1; o < 256; o <<= 1) {
        int u = (t >= o) ? sh[t - o] : 0;
        __syncthreads();
        sh[t] += u;
        __syncthreads();
    }
    if (i < NN) rowptr[i] = sh[t] - v;
    if (t == 255) bsum[b] = sh[255];
}

__global__ __launch_bounds__(256) void k_scan2(int* __restrict__ bsum, int nb) {
    __shared__ int sh[256];
    int t = threadIdx.x;
    int v = (t < nb) ? bsum[t] : 0;
    sh[t] = v;
    __syncthreads();
    #pragma unroll
    for (int o = 1; o < 256; o <<= 1) {
        int u = (t >= o) ? sh[t - o] : 0;
        __syncthreads();
        sh[t] += u;
        __syncthreads();
    }
    if (t < nb) bsum[t] = sh[t] - v;
}

__global__ __launch_bounds__(256) void k_scan3(int* __restrict__ rowptr,
                                               const int* __restrict__ bsum,
                                               int* __restrict__ cursor) {
    int b = blockIdx.x, t = threadIdx.x;
    int i = b * 256 + t;
    if (i < NN) {
        int v = rowptr[i] + bsum[b];
        rowptr[i] = v;
        cursor[i] = v;
    }
    if (i == 0) rowptr[NN] = NE;
}

// epack[pos] = src | (rel<<16)
__global__ void k_fill(const int* __restrict__ dst, const int* __restrict__ src,
                       const int* __restrict__ rel, int* __restrict__ cursor,
                       int* __restrict__ epack) {
    for (int e = blockIdx.x * blockDim.x + threadIdx.x; e < NE;
         e += gridDim.x * blockDim.x) {
        int pos = atomicAdd(&cursor[dst[e]], 1);
        epack[pos] = src[e] | (rel[e] << 16);
    }
}

// ---------- h0 gather (f32 out slice + f16 shadow) ----------
__global__ void k_copy_h0(const int* __restrict__ node_ids,
                          const float* __restrict__ ent,
                          float* __restrict__ out,
                          f16* __restrict__ hf) {
    int i = blockIdx.x * blockDim.x + threadIdx.x;
    if (i >= NN * DD) return;
    int n = i >> 6, d = i & 63;
    float v = ent[(size_t)node_ids[n] * DD + d];
    out[(size_t)n * OSTRIDE + d] = v;
    hf[(size_t)n * DD + d] = (f16)v;
}

// ---------- W -> f16 tables: wf[r][d][E], wtf[r][E][d] ----------
__global__ void k_wprep(const float* __restrict__ W, f16* __restrict__ wf,
                        f16* __restrict__ wtf) {
    int i = blockIdx.x * blockDim.x + threadIdx.x;   // 16*64*64 = 65536
    if (i >= NR * DD * DD) return;
    int r = i >> 12, rem = i & 4095, d = rem >> 6, E = rem & 63;
    f16 v = (f16)W[i];
    wf[i] = v;
    wtf[(r << 12) | (E << 6) | d] = v;
}

// ---------- FUSED: q compute in LDS (f16 MFMA) + edge softmax/aggregate ----------
// Block = 16 dst nodes, 1024 threads = 16 waves.
// Phase 1: wave w computes q[*, r=w] for the tile into q_lds (no HBM).
// Phase 2: wave w = node n0+w; 8x8-lane edge groups, fdot2, no-max softmax.
// Software pipelined: first edge meta + h row are prefetched BEFORE phase 1
// (gather latency hides under MFMA); the loop prefetches step k+1 during k.
__global__ __launch_bounds__(1024) void k_fused9(const f16* __restrict__ hf,
                                                 const f16* __restrict__ wf,
                                                 const f16* __restrict__ wtf,
                                                 const float* __restrict__ relE,
                                                 const int* __restrict__ rowptr,
                                                 const int* __restrict__ epack,
                                                 float* __restrict__ h_nb) {
    __shared__ __align__(16) f16 q_lds[16 * QSTRIDE];   // [ni][r*64+d], 33KB
    __shared__ __align__(16) f16 u_lds[16][16][72];     // per-wave slice, 37KB
    int n0 = blockIdx.x * 16;
    int t  = threadIdx.x;
    int w  = t >> 6, l = t & 63;
    int l15 = l & 15, lg = l >> 4;
    int r = w;
    int g  = l >> 3;       // phase-2 edge group 0..7
    int d8 = l & 7;        // phase-2 dim cluster

    // ---- Phase-2 prefetch (issued before phase 1; latency hides under MFMA) ----
    int n = n0 + w;
    int row0 = 0, row1 = 0;
    if (n < NN) { row0 = rowptr[n]; row1 = rowptr[n + 1]; }
    int deg = row1 - row0;
    int safeRow = row0 < (NE - 1) ? row0 : (NE - 1);
    int idx = row0 + g;
    bool ok = idx < row1;
    int p = 0;
    f16x8 hv = {};
    if (deg > 0) {
        p = epack[ok ? idx : safeRow];
        int s = p & 0xffff;
        hv = *(const f16x8*)(hf + ((size_t)s << 6) + (d8 << 3));
    }

    // ---- Phase 1: q[m, r, :] = W_r @ tanh(h[m,:]@W_r + e_r) ----
    {
        int ar = n0 + l15; if (ar >= NN) ar = NN - 1;
        const f16* ap = hf + (size_t)ar * DD + lg * 8;
        f16x8 a0 = *(const f16x8*)ap;
        f16x8 a1 = *(const f16x8*)(ap + 32);

        f32x4 acc[4];
        #pragma unroll
        for (int nt = 0; nt < 4; ++nt) acc[nt] = (f32x4){0.f, 0.f, 0.f, 0.f};
        const f16* wtr = wtf + (r << 12);
        #pragma unroll
        for (int nt = 0; nt < 4; ++nt) {
            const f16* bp = wtr + (nt * 16 + l15) * DD + lg * 8;
            f16x8 b0 = *(const f16x8*)bp;
            f16x8 b1 = *(const f16x8*)(bp + 32);
            acc[nt] = __builtin_amdgcn_mfma_f32_16x16x32_f16(a0, b0, acc[nt], 0, 0, 0);
            acc[nt] = __builtin_amdgcn_mfma_f32_16x16x32_f16(a1, b1, acc[nt], 0, 0, 0);
        }

        #pragma unroll
        for (int nt = 0; nt < 4; ++nt) {
            int E = nt * 16 + l15;
            float er = relE[r * DD + E];
            #pragma unroll
            for (int reg = 0; reg < 4; ++reg)
                u_lds[w][lg * 4 + reg][E] = (f16)tanh_fast(acc[nt][reg] + er);
        }
        asm volatile("s_waitcnt lgkmcnt(0)" ::: "memory");

        const f16* up = &u_lds[w][l15][lg * 8];
        f16x8 u0 = *(const f16x8*)up;
        f16x8 u1 = *(const f16x8*)(up + 32);

        f32x4 q4[4];
        #pragma unroll
        for (int nt = 0; nt < 4; ++nt) q4[nt] = (f32x4){0.f, 0.f, 0.f, 0.f};
        const f16* wr = wf + (r << 12);
        #pragma unroll
        for (int nt = 0; nt < 4; ++nt) {
            const f16* bp = wr + (nt * 16 + l15) * DD + lg * 8;
            f16x8 b0 = *(const f16x8*)bp;
            f16x8 b1 = *(const f16x8*)(bp + 32);
            q4[nt] = __builtin_amdgcn_mfma_f32_16x16x32_f16(u0, b0, q4[nt], 0, 0, 0);
            q4[nt] = __builtin_amdgcn_mfma_f32_16x16x32_f16(u1, b1, q4[nt], 0, 0, 0);
        }

        #pragma unroll
        for (int reg = 0; reg < 4; ++reg) {
            f16* qp = q_lds + (lg * 4 + reg) * QSTRIDE + r * 64 + l15;
            #pragma unroll
            for (int nt = 0; nt < 4; ++nt)
                qp[nt * 16] = (f16)q4[nt][reg];
        }
    }
    __syncthreads();

    // ---- Phase 2: node n0+w; group g handles edges row0 + 8k + g ----
    if (n >= NN) return;
    const f16* ql = q_lds + w * QSTRIDE;

    float zr = 0.f;
    float a[8] = {};

    if (deg > 0) {
        int steps = (deg + 7) >> 3;
        for (int k = 0; k < steps; ++k) {
            // prefetch step k+1 (harmless dummy on last iter)
            int idxn = idx + 8;
            bool okn = idxn < row1;
            int pn = epack[okn ? idxn : safeRow];
            int sn = pn & 0xffff;
            f16x8 hvn = *(const f16x8*)(hf + ((size_t)sn << 6) + (d8 << 3));

            int rr = p >> 16;
            f16x8 qv = *(const f16x8*)(ql + (rr << 6) + (d8 << 3));
            float dp = 0.f;
            #pragma unroll
            for (int j = 0; j < 4; ++j) {
                f16x2 ha = {hv[2 * j], hv[2 * j + 1]};
                f16x2 qa = {qv[2 * j], qv[2 * j + 1]};
                dp = dot2acc(ha, qa, dp);
            }
            dp += __shfl_xor(dp, 1, 64);
            dp += __shfl_xor(dp, 2, 64);
            dp += __shfl_xor(dp, 4, 64);
            float wg = ok ? __expf(dp) : 0.f;   // scores bounded; softmax shift-invariant
            zr += wg;
            #pragma unroll
            for (int j = 0; j < 8; ++j)
                a[j] = fmaf(wg, (float)hv[j], a[j]);

            idx = idxn; ok = okn; p = pn; hv = hvn;
        }
    }

    // merge the 8 group partial sums
    #pragma unroll
    for (int o = 8; o < 64; o <<= 1) {
        zr += __shfl_xor(zr, o, 64);
        #pragma unroll
        for (int j = 0; j < 8; ++j)
            a[j] += __shfl_xor(a[j], o, 64);
    }

    if (g == 0) {
        float inv = (deg > 0) ? 1.f / zr : 0.f;
        float4* dst4 = (float4*)&h_nb[((size_t)n << 6) + (d8 << 3)];
        dst4[0] = make_float4(a[0] * inv, a[1] * inv, a[2] * inv, a[3] * inv);
        dst4[1] = make_float4(a[4] * inv, a[5] * inv, a[6] * inv, a[7] * inv);
    }
}

// ---------- epilogue GEMM (f32) + f16 shadow of new h ----------
__global__ __launch_bounds__(256) void k_out2(const float* __restrict__ h_nb,
                                              const float* __restrict__ ra,
                                              const float* __restrict__ rb,
                                              float* __restrict__ out,
                                              int off_in, int off_out,
                                              f16* __restrict__ hf) {
    __shared__ __align__(16) float v1s[64][68];
    __shared__ __align__(16) float v2s[64][68];
    __shared__ __align__(16) float ws[2][64][64];
    int t = threadIdx.x;
    int n0 = blockIdx.x * 64;

    for (int i = t; i < 1024; i += 256) {
        int ni = i >> 4, c4 = (i & 15) * 4;
        int n = n0 + ni;
        float4 hv = make_float4(0.f, 0.f, 0.f, 0.f);
        float4 nb = make_float4(0.f, 0.f, 0.f, 0.f);
        if (n < NN) {
            hv = *(const float4*)&out[(size_t)n * OSTRIDE + off_in + c4];
            nb = *(const float4*)&h_nb[(size_t)n * DD + c4];
        }
        v1s[c4 + 0][ni] = hv.x + nb.x;  v2s[c4 + 0][ni] = hv.x * nb.x;
        v1s[c4 + 1][ni] = hv.y + nb.y;  v2s[c4 + 1][ni] = hv.y * nb.y;
        v1s[c4 + 2][ni] = hv.z + nb.z;  v2s[c4 + 2][ni] = hv.z * nb.z;
        v1s[c4 + 3][ni] = hv.w + nb.w;  v2s[c4 + 3][ni] = hv.w * nb.w;
    }
    for (int i = t; i < 2048; i += 256) {
        const float* base = (i < 1024) ? ra : rb;
        int rem = i & 1023;
        float4 v = *(const float4*)&base[rem * 4];
        int k = rem >> 4, c4 = (rem & 15) * 4;
        *(float4*)&ws[i >> 10][k][c4] = v;
    }
    __syncthreads();

    int nd0 = (t >> 4) * 4;
    int c0  = (t & 15) * 4;
    float a1[4][4] = {}, a2[4][4] = {};
    #pragma unroll 8
    for (int k = 0; k < 64; ++k) {
        float4 h1 = *(const float4*)&v1s[k][nd0];
        float4 h2 = *(const float4*)&v2s[k][nd0];
        float4 wa = *(const float4*)&ws[0][k][c0];
        float4 wb = *(const float4*)&ws[1][k][c0];
        float x1[4] = {h1.x, h1.y, h1.z, h1.w};
        float x2[4] = {h2.x, h2.y, h2.z, h2.w};
        #pragma unroll
        for (int i = 0; i < 4; ++i) {
            a1[i][0] += x1[i] * wa.x; a1[i][1] += x1[i] * wa.y;
            a1[i][2] += x1[i] * wa.z; a1[i][3] += x1[i] * wa.w;
            a2[i][0] += x2[i] * wb.x; a2[i][1] += x2[i] * wb.y;
            a2[i][2] += x2[i] * wb.z; a2[i][3] += x2[i] * wb.w;
        }
    }
    #pragma unroll
    for (int i = 0; i < 4; ++i) {
        int n = n0 + nd0 + i;
        if (n >= NN) continue;
        float4 o;
        float* po = (float*)&o;
        #pragma unroll
        for (int j = 0; j < 4; ++j) {
            float u1 = a1[i][j], u2 = a2[i][j];
            u1 = u1 > 0.f ? u1 : 0.01f * u1;
            u2 = u2 > 0.f ? u2 : 0.01f * u2;
            po[j] = u1 + u2;
        }
        *(float4*)&out[(size_t)n * OSTRIDE + off_out + c0] = o;
        f16x4 hq = {(f16)o.x, (f16)o.y, (f16)o.z, (f16)o.w};
        *(f16x4*)&hf[(size_t)n * DD + c0] = hq;
    }
}

// ---------- launch ----------
extern "C" void kernel_launch(void* const* d_in, const int* in_sizes, int n_in,
                              void* d_out, int out_size, void* d_ws, size_t ws_size,
                              hipStream_t stream) {
    const int*   node_ids = (const int*)d_in[0];
    const int*   rel_ids  = (const int*)d_in[1];
    const int*   src      = (const int*)d_in[2];
    const int*   dst      = (const int*)d_in[3];
    const float* ent      = (const float*)d_in[4];
    const float* relE     = (const float*)d_in[5];
    const float* W[2]  = {(const float*)d_in[6], (const float*)d_in[7]};
    const float* ra[2] = {(const float*)d_in[8], (const float*)d_in[10]};
    const float* rb[2] = {(const float*)d_in[9], (const float*)d_in[11]};
    float* out = (float*)d_out;

    const size_t hnb_bytes    = (size_t)NN * DD * sizeof(float);       // 12.8 MB
    const size_t hf_bytes     = (size_t)NN * DD * sizeof(f16);         // 6.4 MB
    const size_t wf_bytes     = (size_t)NR * DD * DD * sizeof(f16);    // 128 KB
    const size_t epack_bytes  = (size_t)NE * sizeof(int);              // 3.2 MB
    const size_t rowptr_bytes = (size_t)(NN + 1) * sizeof(int);
    const size_t cnt_bytes    = (size_t)NN * sizeof(int);
    const int    NB_SCAN      = (NN + 255) / 256;   // 196
    const size_t bsum_bytes   = (size_t)256 * sizeof(int);

    char* p = (char*)d_ws;
    float* h_nb   = (float*)p; p += hnb_bytes;
    f16*   hf     = (f16*)p;   p += hf_bytes;
    f16*   wf     = (f16*)p;   p += wf_bytes;
    f16*   wtf    = (f16*)p;   p += wf_bytes;
    int*   epack  = (int*)p;   p += epack_bytes;
    int*   rowptr = (int*)p;   p += rowptr_bytes;
    int*   cnt    = (int*)p;   p += cnt_bytes;
    int*   bsum   = (int*)p;   p += bsum_bytes;
    (void)ws_size;

    // ---- CSR build (shared by both layers) ----
    hipMemsetAsync(cnt, 0, cnt_bytes, stream);
    k_deg  <<<1024, 256, 0, stream>>>(dst, cnt);
    k_scan1<<<NB_SCAN, 256, 0, stream>>>(cnt, rowptr, bsum);
    k_scan2<<<1, 256, 0, stream>>>(bsum, NB_SCAN);
    k_scan3<<<NB_SCAN, 256, 0, stream>>>(rowptr, bsum, cnt);
    k_fill <<<1024, 256, 0, stream>>>(dst, src, rel_ids, cnt, epack);

    // ---- h0 ----
    k_copy_h0<<<(NN * DD + 255) / 256, 256, 0, stream>>>(node_ids, ent, out, hf);

    for (int L = 0; L < 2; ++L) {
        int off_in = L * DD;
        int off_out = (L + 1) * DD;

        k_wprep <<<(NR * DD * DD + 255) / 256, 256, 0, stream>>>(W[L], wf, wtf);
        k_fused9<<<(NN + 15) / 16, 1024, 0, stream>>>(hf, wf, wtf, relE,
                                                      rowptr, epack, h_nb);
        k_out2  <<<(NN + 63) / 64, 256, 0, stream>>>(h_nb, ra[L], rb[L], out,
                                                     off_in, off_out, hf);
    }
}

// Round 17
// 387.048 us; speedup vs baseline: 1.1880x; 1.1880x over previous
//
#include <hip/hip_runtime.h>
#include <hip/hip_bf16.h>
#include <math.h>

#define NN 50000
#define NE 800000
#define NR 16
#define DD 64
#define OSTRIDE 192   // 3*D concat output stride
#define QSTRIDE 1032  // f16 elems per node row in q_lds (1024 + 8 pad)

typedef _Float16 f16;
typedef f16 f16x8 __attribute__((ext_vector_type(8)));
typedef f16 f16x4 __attribute__((ext_vector_type(4)));
typedef f16 f16x2 __attribute__((ext_vector_type(2)));
typedef __attribute__((ext_vector_type(4))) float f32x4;

__device__ inline float tanh_fast(float x) {
    return 1.f - 2.f / (__expf(2.f * x) + 1.f);
}

__device__ inline float dot2acc(f16x2 a, f16x2 b, float c) {
#if __has_builtin(__builtin_amdgcn_fdot2)
    return __builtin_amdgcn_fdot2(a, b, c, false);
#else
    return c + (float)a[0] * (float)b[0] + (float)a[1] * (float)b[1];
#endif
}

// ---------- CSR build ----------
__global__ void k_deg(const int* __restrict__ dst, int* __restrict__ cnt) {
    for (int e = blockIdx.x * blockDim.x + threadIdx.x; e < NE;
         e += gridDim.x * blockDim.x)
        atomicAdd(&cnt[dst[e]], 1);
}

__global__ __launch_bounds__(256) void k_scan1(const int* __restrict__ cnt,
                                               int* __restrict__ rowptr,
                                               int* __restrict__ bsum) {
    __shared__ int sh[256];
    int b = blockIdx.x, t = threadIdx.x;
    int i = b * 256 + t;
    int v = (i < NN) ? cnt[i] : 0;
    sh[t] = v;
    __syncthreads();
    #pragma unroll
    for (int o = 1; o < 256; o <<= 1) {
        int u = (t >= o) ? sh[t - o] : 0;
        __syncthreads();
        sh[t] += u;
        __syncthreads();
    }
    if (i < NN) rowptr[i] = sh[t] - v;
    if (t == 255) bsum[b] = sh[255];
}

__global__ __launch_bounds__(256) void k_scan2(int* __restrict__ bsum, int nb) {
    __shared__ int sh[256];
    int t = threadIdx.x;
    int v = (t < nb) ? bsum[t] : 0;
    sh[t] = v;
    __syncthreads();
    #pragma unroll
    for (int o = 1; o < 256; o <<= 1) {
        int u = (t >= o) ? sh[t - o] : 0;
        __syncthreads();
        sh[t] += u;
        __syncthreads();
    }
    if (t < nb) bsum[t] = sh[t] - v;
}

__global__ __launch_bounds__(256) void k_scan3(int* __restrict__ rowptr,
                                               const int* __restrict__ bsum,
                                               int* __restrict__ cursor) {
    int b = blockIdx.x, t = threadIdx.x;
    int i = b * 256 + t;
    if (i < NN) {
        int v = rowptr[i] + bsum[b];
        rowptr[i] = v;
        cursor[i] = v;
    }
    if (i == 0) rowptr[NN] = NE;
}

// epack[pos] = src | (rel<<16)
__global__ void k_fill(const int* __restrict__ dst, const int* __restrict__ src,
                       const int* __restrict__ rel, int* __restrict__ cursor,
                       int* __restrict__ epack) {
    for (int e = blockIdx.x * blockDim.x + threadIdx.x; e < NE;
         e += gridDim.x * blockDim.x) {
        int pos = atomicAdd(&cursor[dst[e]], 1);
        epack[pos] = src[e] | (rel[e] << 16);
    }
}

// ---------- h0 gather (f32 out slice + f16 shadow) ----------
__global__ void k_copy_h0(const int* __restrict__ node_ids,
                          const float* __restrict__ ent,
                          float* __restrict__ out,
                          f16* __restrict__ hf) {
    int i = blockIdx.x * blockDim.x + threadIdx.x;
    if (i >= NN * DD) return;
    int n = i >> 6, d = i & 63;
    float v = ent[(size_t)node_ids[n] * DD + d];
    out[(size_t)n * OSTRIDE + d] = v;
    hf[(size_t)n * DD + d] = (f16)v;
}

// ---------- W -> f16 tables: wf[r][d][E], wtf[r][E][d] ----------
__global__ void k_wprep(const float* __restrict__ W, f16* __restrict__ wf,
                        f16* __restrict__ wtf) {
    int i = blockIdx.x * blockDim.x + threadIdx.x;   // 16*64*64 = 65536
    if (i >= NR * DD * DD) return;
    int r = i >> 12, rem = i & 4095, d = rem >> 6, E = rem & 63;
    f16 v = (f16)W[i];
    wf[i] = v;
    wtf[(r << 12) | (E << 6) | d] = v;
}

// ---------- ra/rb -> f16 transposed tables: rat[d'][d], rbt[d'][d] ----------
__global__ void k_rprep(const float* __restrict__ ra, const float* __restrict__ rb,
                        f16* __restrict__ rat, f16* __restrict__ rbt) {
    int i = blockIdx.x * blockDim.x + threadIdx.x;   // 4096
    if (i >= DD * DD) return;
    int d = i >> 6, dp = i & 63;
    rat[dp * 64 + d] = (f16)ra[i];
    rbt[dp * 64 + d] = (f16)rb[i];
}

// ---------- FULLY FUSED: q (MFMA, LDS) + edge softmax/agg + epilogue GEMM ----------
// Block = 16 dst nodes, 1024 threads = 16 waves.
// hfin is READ-ONLY in this kernel (phase-1 A frags + phase-2 gathers);
// hfout is a DIFFERENT buffer (ping-pong) -> no cross-block read/write race.
// Phase 1: wave w computes q[*, r=w] for the tile into q_lds (no HBM).
// Phase 2: wave w = node n0+w; 8x8-lane edge groups, fdot2, no-max softmax;
//          g==0 lanes write v1=h+nb, v2=h*nb (f16) into the dead q_lds row.
// Phase 3: waves 0-3 do the 16x64x64 epilogue as 4 MFMA vs rat/rbt (B^T, L2-hot),
//          leaky+add, store f32 out slice + f16 hfout shadow. (NN%16==0: no tail.)
__global__ __launch_bounds__(1024) void k_fused10(const f16* __restrict__ hfin,
                                                  const f16* __restrict__ wf,
                                                  const f16* __restrict__ wtf,
                                                  const f16* __restrict__ rat,
                                                  const f16* __restrict__ rbt,
                                                  const float* __restrict__ relE,
                                                  const int* __restrict__ rowptr,
                                                  const int* __restrict__ epack,
                                                  float* __restrict__ out,
                                                  int off_in, int off_out,
                                                  f16* __restrict__ hfout) {
    __shared__ __align__(16) f16 q_lds[16 * QSTRIDE];   // [ni][r*64+d], 33KB
    __shared__ __align__(16) f16 u_lds[16][16][72];     // per-wave slice, 37KB
    int n0 = blockIdx.x * 16;
    int t  = threadIdx.x;
    int w  = t >> 6, l = t & 63;
    int l15 = l & 15, lg = l >> 4;
    int r = w;

    // ---- Phase 1: q[m, r, :] = W_r @ tanh(h[m,:]@W_r + e_r) ----
    {
        int ar = n0 + l15;
        const f16* ap = hfin + (size_t)ar * DD + lg * 8;
        f16x8 a0 = *(const f16x8*)ap;
        f16x8 a1 = *(const f16x8*)(ap + 32);

        f32x4 acc[4];
        #pragma unroll
        for (int nt = 0; nt < 4; ++nt) acc[nt] = (f32x4){0.f, 0.f, 0.f, 0.f};
        const f16* wtr = wtf + (r << 12);
        #pragma unroll
        for (int nt = 0; nt < 4; ++nt) {
            const f16* bp = wtr + (nt * 16 + l15) * DD + lg * 8;
            f16x8 b0 = *(const f16x8*)bp;
            f16x8 b1 = *(const f16x8*)(bp + 32);
            acc[nt] = __builtin_amdgcn_mfma_f32_16x16x32_f16(a0, b0, acc[nt], 0, 0, 0);
            acc[nt] = __builtin_amdgcn_mfma_f32_16x16x32_f16(a1, b1, acc[nt], 0, 0, 0);
        }

        #pragma unroll
        for (int nt = 0; nt < 4; ++nt) {
            int E = nt * 16 + l15;
            float er = relE[r * DD + E];
            #pragma unroll
            for (int reg = 0; reg < 4; ++reg)
                u_lds[w][lg * 4 + reg][E] = (f16)tanh_fast(acc[nt][reg] + er);
        }
        asm volatile("s_waitcnt lgkmcnt(0)" ::: "memory");

        const f16* up = &u_lds[w][l15][lg * 8];
        f16x8 u0 = *(const f16x8*)up;
        f16x8 u1 = *(const f16x8*)(up + 32);

        f32x4 q4[4];
        #pragma unroll
        for (int nt = 0; nt < 4; ++nt) q4[nt] = (f32x4){0.f, 0.f, 0.f, 0.f};
        const f16* wr = wf + (r << 12);
        #pragma unroll
        for (int nt = 0; nt < 4; ++nt) {
            const f16* bp = wr + (nt * 16 + l15) * DD + lg * 8;
            f16x8 b0 = *(const f16x8*)bp;
            f16x8 b1 = *(const f16x8*)(bp + 32);
            q4[nt] = __builtin_amdgcn_mfma_f32_16x16x32_f16(u0, b0, q4[nt], 0, 0, 0);
            q4[nt] = __builtin_amdgcn_mfma_f32_16x16x32_f16(u1, b1, q4[nt], 0, 0, 0);
        }

        #pragma unroll
        for (int reg = 0; reg < 4; ++reg) {
            f16* qp = q_lds + (lg * 4 + reg) * QSTRIDE + r * 64 + l15;
            #pragma unroll
            for (int nt = 0; nt < 4; ++nt)
                qp[nt * 16] = (f16)q4[nt][reg];
        }
    }
    __syncthreads();

    // ---- Phase 2: node n0+w; group g (8 lanes) handles edges row0 + 8k + g ----
    int n = n0 + w;
    const f16* ql = q_lds + w * QSTRIDE;
    int row0 = rowptr[n], row1 = rowptr[n + 1];
    int deg = row1 - row0;
    int g  = l >> 3;       // group id 0..7
    int d8 = l & 7;        // element cluster: elems 8*d8 .. +7

    float zr = 0.f;
    float a[8] = {};

    int steps = (deg + 7) >> 3;
    for (int k = 0; k < steps; ++k) {
        int idx = row0 + (k << 3) + g;
        bool ok = idx < row1;
        int p = epack[ok ? idx : row0];
        int s = p & 0xffff, rr = p >> 16;
        f16x8 hv = *(const f16x8*)(hfin + ((size_t)s << 6) + (d8 << 3));
        f16x8 qv = *(const f16x8*)(ql + (rr << 6) + (d8 << 3));
        float dp = 0.f;
        #pragma unroll
        for (int j = 0; j < 4; ++j) {
            f16x2 ha = {hv[2 * j], hv[2 * j + 1]};
            f16x2 qa = {qv[2 * j], qv[2 * j + 1]};
            dp = dot2acc(ha, qa, dp);
        }
        dp += __shfl_xor(dp, 1, 64);
        dp += __shfl_xor(dp, 2, 64);
        dp += __shfl_xor(dp, 4, 64);
        float wg = ok ? __expf(dp) : 0.f;   // scores bounded; softmax shift-invariant
        zr += wg;
        #pragma unroll
        for (int j = 0; j < 8; ++j)
            a[j] = fmaf(wg, (float)hv[j], a[j]);
    }

    // merge the 8 group partial sums
    #pragma unroll
    for (int o = 8; o < 64; o <<= 1) {
        zr += __shfl_xor(zr, o, 64);
        #pragma unroll
        for (int j = 0; j < 8; ++j)
            a[j] += __shfl_xor(a[j], o, 64);
    }

    // g==0 lanes (d8 = 0..7) hold the full row; write v1, v2 into our q_lds row
    if (g == 0) {
        float inv = (deg > 0) ? 1.f / zr : 0.f;
        const float* hp = &out[(size_t)n * OSTRIDE + off_in + (d8 << 3)];
        float4 h0 = *(const float4*)hp;
        float4 h1 = *(const float4*)(hp + 4);
        float hh[8] = {h0.x, h0.y, h0.z, h0.w, h1.x, h1.y, h1.z, h1.w};
        f16x8 v1v, v2v;
        #pragma unroll
        for (int j = 0; j < 8; ++j) {
            float nb = a[j] * inv;
            v1v[j] = (f16)(hh[j] + nb);
            v2v[j] = (f16)(hh[j] * nb);
        }
        *(f16x8*)(q_lds + w * QSTRIDE + (d8 << 3)) = v1v;
        *(f16x8*)(q_lds + w * QSTRIDE + 256 + (d8 << 3)) = v2v;
    }
    __syncthreads();

    // ---- Phase 3: epilogue OUT = leaky(V1@ra) + leaky(V2@rb), waves 0-3 ----
    if (w < 4) {
        const f16* v1p = q_lds + (size_t)l15 * QSTRIDE + lg * 8;
        f16x8 a10 = *(const f16x8*)v1p;
        f16x8 a11 = *(const f16x8*)(v1p + 32);
        const f16* v2p = v1p + 256;
        f16x8 a20 = *(const f16x8*)v2p;
        f16x8 a21 = *(const f16x8*)(v2p + 32);

        const f16* bra = rat + (w * 16 + l15) * 64 + lg * 8;   // B^T rows = ra cols
        f16x8 b10 = *(const f16x8*)bra;
        f16x8 b11 = *(const f16x8*)(bra + 32);
        const f16* brb = rbt + (w * 16 + l15) * 64 + lg * 8;
        f16x8 b20 = *(const f16x8*)brb;
        f16x8 b21 = *(const f16x8*)(brb + 32);

        f32x4 o1 = (f32x4){0.f, 0.f, 0.f, 0.f};
        f32x4 o2 = (f32x4){0.f, 0.f, 0.f, 0.f};
        o1 = __builtin_amdgcn_mfma_f32_16x16x32_f16(a10, b10, o1, 0, 0, 0);
        o1 = __builtin_amdgcn_mfma_f32_16x16x32_f16(a11, b11, o1, 0, 0, 0);
        o2 = __builtin_amdgcn_mfma_f32_16x16x32_f16(a20, b20, o2, 0, 0, 0);
        o2 = __builtin_amdgcn_mfma_f32_16x16x32_f16(a21, b21, o2, 0, 0, 0);

        int dp = w * 16 + l15;                   // output dim
        #pragma unroll
        for (int reg = 0; reg < 4; ++reg) {
            int node = n0 + lg * 4 + reg;        // C row = node
            float u1 = o1[reg], u2 = o2[reg];
            u1 = u1 > 0.f ? u1 : 0.01f * u1;
            u2 = u2 > 0.f ? u2 : 0.01f * u2;
            float v = u1 + u2;
            out[(size_t)node * OSTRIDE + off_out + dp] = v;
            hfout[(size_t)node * DD + dp] = (f16)v;
        }
    }
}

// ---------- launch ----------
extern "C" void kernel_launch(void* const* d_in, const int* in_sizes, int n_in,
                              void* d_out, int out_size, void* d_ws, size_t ws_size,
                              hipStream_t stream) {
    const int*   node_ids = (const int*)d_in[0];
    const int*   rel_ids  = (const int*)d_in[1];
    const int*   src      = (const int*)d_in[2];
    const int*   dst      = (const int*)d_in[3];
    const float* ent      = (const float*)d_in[4];
    const float* relE     = (const float*)d_in[5];
    const float* W[2]  = {(const float*)d_in[6], (const float*)d_in[7]};
    const float* ra[2] = {(const float*)d_in[8], (const float*)d_in[10]};
    const float* rb[2] = {(const float*)d_in[9], (const float*)d_in[11]};
    float* out = (float*)d_out;

    const size_t hf_bytes     = (size_t)NN * DD * sizeof(f16);         // 6.4 MB
    const size_t wf_bytes     = (size_t)NR * DD * DD * sizeof(f16);    // 128 KB
    const size_t rt_bytes     = (size_t)DD * DD * sizeof(f16);         // 8 KB
    const size_t epack_bytes  = (size_t)NE * sizeof(int);              // 3.2 MB
    const size_t rowptr_bytes = (size_t)(NN + 1) * sizeof(int);
    const size_t cnt_bytes    = (size_t)NN * sizeof(int);
    const int    NB_SCAN      = (NN + 255) / 256;   // 196
    const size_t bsum_bytes   = (size_t)256 * sizeof(int);

    char* p = (char*)d_ws;
    f16*   hf     = (f16*)p;   p += hf_bytes;
    f16*   hf2    = (f16*)p;   p += hf_bytes;   // ping-pong shadow (race fix)
    f16*   wf     = (f16*)p;   p += wf_bytes;
    f16*   wtf    = (f16*)p;   p += wf_bytes;
    f16*   rat    = (f16*)p;   p += rt_bytes;
    f16*   rbt    = (f16*)p;   p += rt_bytes;
    int*   epack  = (int*)p;   p += epack_bytes;
    int*   rowptr = (int*)p;   p += rowptr_bytes;
    int*   cnt    = (int*)p;   p += cnt_bytes;
    int*   bsum   = (int*)p;   p += bsum_bytes;
    (void)ws_size;

    // ---- CSR build (shared by both layers) ----
    hipMemsetAsync(cnt, 0, cnt_bytes, stream);
    k_deg  <<<1024, 256, 0, stream>>>(dst, cnt);
    k_scan1<<<NB_SCAN, 256, 0, stream>>>(cnt, rowptr, bsum);
    k_scan2<<<1, 256, 0, stream>>>(bsum, NB_SCAN);
    k_scan3<<<NB_SCAN, 256, 0, stream>>>(rowptr, bsum, cnt);
    k_fill <<<1024, 256, 0, stream>>>(dst, src, rel_ids, cnt, epack);

    // ---- h0 ----
    k_copy_h0<<<(NN * DD + 255) / 256, 256, 0, stream>>>(node_ids, ent, out, hf);

    f16* hin  = hf;
    f16* hout = hf2;
    for (int L = 0; L < 2; ++L) {
        int off_in = L * DD;
        int off_out = (L + 1) * DD;

        k_wprep <<<(NR * DD * DD + 255) / 256, 256, 0, stream>>>(W[L], wf, wtf);
        k_rprep <<<(DD * DD + 255) / 256, 256, 0, stream>>>(ra[L], rb[L], rat, rbt);
        k_fused10<<<NN / 16, 1024, 0, stream>>>(hin, wf, wtf, rat, rbt, relE,
                                                rowptr, epack, out,
                                                off_in, off_out, hout);
        f16* tmp = hin; hin = hout; hout = tmp;
    }
}

// Round 18
// 376.038 us; speedup vs baseline: 1.2228x; 1.0293x over previous
//
#include <hip/hip_runtime.h>
#include <hip/hip_bf16.h>
#include <math.h>

#define NN 50000
#define NE 800000
#define NR 16
#define DD 64
#define OSTRIDE 192   // 3*D concat output stride
#define QSTRIDE 1032  // f16 elems per node row in q_lds (1024 + 8 pad)

typedef _Float16 f16;
typedef f16 f16x8 __attribute__((ext_vector_type(8)));
typedef f16 f16x2 __attribute__((ext_vector_type(2)));
typedef __attribute__((ext_vector_type(4))) float f32x4;

__device__ inline float tanh_fast(float x) {
    return 1.f - 2.f / (__expf(2.f * x) + 1.f);
}

__device__ inline float dot2acc(f16x2 a, f16x2 b, float c) {
#if __has_builtin(__builtin_amdgcn_fdot2)
    return __builtin_amdgcn_fdot2(a, b, c, false);
#else
    return c + (float)a[0] * (float)b[0] + (float)a[1] * (float)b[1];
#endif
}

// cross-lane adds on the VALU (DPP) instead of the DS pipe where possible
#if __has_builtin(__builtin_amdgcn_update_dpp)
__device__ inline float xor1_add(float x) {   // quad_perm [1,0,3,2]
    return x + __int_as_float(__builtin_amdgcn_update_dpp(
        0, __float_as_int(x), 0xB1, 0xF, 0xF, true));
}
__device__ inline float xor2_add(float x) {   // quad_perm [2,3,0,1]
    return x + __int_as_float(__builtin_amdgcn_update_dpp(
        0, __float_as_int(x), 0x4E, 0xF, 0xF, true));
}
__device__ inline float xor8_add(float x) {   // row_ror:8 == xor8 within 16-row
    return x + __int_as_float(__builtin_amdgcn_update_dpp(
        0, __float_as_int(x), 0x108, 0xF, 0xF, true));
}
#else
__device__ inline float xor1_add(float x) { return x + __shfl_xor(x, 1, 64); }
__device__ inline float xor2_add(float x) { return x + __shfl_xor(x, 2, 64); }
__device__ inline float xor8_add(float x) { return x + __shfl_xor(x, 8, 64); }
#endif

// ---------- CSR build ----------
__global__ void k_deg(const int* __restrict__ dst, int* __restrict__ cnt) {
    for (int e = blockIdx.x * blockDim.x + threadIdx.x; e < NE;
         e += gridDim.x * blockDim.x)
        atomicAdd(&cnt[dst[e]], 1);
}

__global__ __launch_bounds__(256) void k_scan1(const int* __restrict__ cnt,
                                               int* __restrict__ rowptr,
                                               int* __restrict__ bsum) {
    __shared__ int sh[256];
    int b = blockIdx.x, t = threadIdx.x;
    int i = b * 256 + t;
    int v = (i < NN) ? cnt[i] : 0;
    sh[t] = v;
    __syncthreads();
    #pragma unroll
    for (int o = 1; o < 256; o <<= 1) {
        int u = (t >= o) ? sh[t - o] : 0;
        __syncthreads();
        sh[t] += u;
        __syncthreads();
    }
    if (i < NN) rowptr[i] = sh[t] - v;
    if (t == 255) bsum[b] = sh[255];
}

__global__ __launch_bounds__(256) void k_scan2(int* __restrict__ bsum, int nb) {
    __shared__ int sh[256];
    int t = threadIdx.x;
    int v = (t < nb) ? bsum[t] : 0;
    sh[t] = v;
    __syncthreads();
    #pragma unroll
    for (int o = 1; o < 256; o <<= 1) {
        int u = (t >= o) ? sh[t - o] : 0;
        __syncthreads();
        sh[t] += u;
        __syncthreads();
    }
    if (t < nb) bsum[t] = sh[t] - v;
}

__global__ __launch_bounds__(256) void k_scan3(int* __restrict__ rowptr,
                                               const int* __restrict__ bsum,
                                               int* __restrict__ cursor) {
    int b = blockIdx.x, t = threadIdx.x;
    int i = b * 256 + t;
    if (i < NN) {
        int v = rowptr[i] + bsum[b];
        rowptr[i] = v;
        cursor[i] = v;
    }
    if (i == 0) rowptr[NN] = NE;
}

// epack[pos] = src | (rel<<16)
__global__ void k_fill(const int* __restrict__ dst, const int* __restrict__ src,
                       const int* __restrict__ rel, int* __restrict__ cursor,
                       int* __restrict__ epack) {
    for (int e = blockIdx.x * blockDim.x + threadIdx.x; e < NE;
         e += gridDim.x * blockDim.x) {
        int pos = atomicAdd(&cursor[dst[e]], 1);
        epack[pos] = src[e] | (rel[e] << 16);
    }
}

// ---------- h0 gather (f32 out slice + f16 shadow) ----------
__global__ void k_copy_h0(const int* __restrict__ node_ids,
                          const float* __restrict__ ent,
                          float* __restrict__ out,
                          f16* __restrict__ hf) {
    int i = blockIdx.x * blockDim.x + threadIdx.x;
    if (i >= NN * DD) return;
    int n = i >> 6, d = i & 63;
    float v = ent[(size_t)node_ids[n] * DD + d];
    out[(size_t)n * OSTRIDE + d] = v;
    hf[(size_t)n * DD + d] = (f16)v;
}

// ---------- combined prep: W->wf/wtf, ra/rb->rat/rbt (f16, transposed) ----------
__global__ void k_prep(const float* __restrict__ W,
                       const float* __restrict__ ra, const float* __restrict__ rb,
                       f16* __restrict__ wf, f16* __restrict__ wtf,
                       f16* __restrict__ rat, f16* __restrict__ rbt) {
    int i = blockIdx.x * blockDim.x + threadIdx.x;
    if (i < NR * DD * DD) {
        int r = i >> 12, rem = i & 4095, d = rem >> 6, E = rem & 63;
        f16 v = (f16)W[i];
        wf[i] = v;
        wtf[(r << 12) | (E << 6) | d] = v;
    }
    if (i < DD * DD) {
        int d = i >> 6, dp = i & 63;
        rat[dp * 64 + d] = (f16)ra[i];
        rbt[dp * 64 + d] = (f16)rb[i];
    }
}

// ---------- FULLY FUSED: q (MFMA, LDS) + edge softmax/agg + epilogue GEMM ----------
// Block = 16 dst nodes, 1024 threads = 16 waves. hfin READ-ONLY; hfout ping-pong.
__global__ __launch_bounds__(1024) void k_fused10(const f16* __restrict__ hfin,
                                                  const f16* __restrict__ wf,
                                                  const f16* __restrict__ wtf,
                                                  const f16* __restrict__ rat,
                                                  const f16* __restrict__ rbt,
                                                  const float* __restrict__ relE,
                                                  const int* __restrict__ rowptr,
                                                  const int* __restrict__ epack,
                                                  float* __restrict__ out,
                                                  int off_in, int off_out,
                                                  f16* __restrict__ hfout) {
    __shared__ __align__(16) f16 q_lds[16 * QSTRIDE];   // [ni][r*64+d], 33KB
    __shared__ __align__(16) f16 u_lds[16][16][72];     // per-wave slice, 37KB
    int n0 = blockIdx.x * 16;
    int t  = threadIdx.x;
    int w  = t >> 6, l = t & 63;
    int l15 = l & 15, lg = l >> 4;
    int r = w;

    // ---- Phase 1: q[m, r, :] = W_r @ tanh(h[m,:]@W_r + e_r) ----
    {
        int ar = n0 + l15;
        const f16* ap = hfin + (size_t)ar * DD + lg * 8;
        f16x8 a0 = *(const f16x8*)ap;
        f16x8 a1 = *(const f16x8*)(ap + 32);

        f32x4 acc[4];
        #pragma unroll
        for (int nt = 0; nt < 4; ++nt) acc[nt] = (f32x4){0.f, 0.f, 0.f, 0.f};
        const f16* wtr = wtf + (r << 12);
        #pragma unroll
        for (int nt = 0; nt < 4; ++nt) {
            const f16* bp = wtr + (nt * 16 + l15) * DD + lg * 8;
            f16x8 b0 = *(const f16x8*)bp;
            f16x8 b1 = *(const f16x8*)(bp + 32);
            acc[nt] = __builtin_amdgcn_mfma_f32_16x16x32_f16(a0, b0, acc[nt], 0, 0, 0);
            acc[nt] = __builtin_amdgcn_mfma_f32_16x16x32_f16(a1, b1, acc[nt], 0, 0, 0);
        }

        #pragma unroll
        for (int nt = 0; nt < 4; ++nt) {
            int E = nt * 16 + l15;
            float er = relE[r * DD + E];
            #pragma unroll
            for (int reg = 0; reg < 4; ++reg)
                u_lds[w][lg * 4 + reg][E] = (f16)tanh_fast(acc[nt][reg] + er);
        }
        asm volatile("s_waitcnt lgkmcnt(0)" ::: "memory");

        const f16* up = &u_lds[w][l15][lg * 8];
        f16x8 u0 = *(const f16x8*)up;
        f16x8 u1 = *(const f16x8*)(up + 32);

        f32x4 q4[4];
        #pragma unroll
        for (int nt = 0; nt < 4; ++nt) q4[nt] = (f32x4){0.f, 0.f, 0.f, 0.f};
        const f16* wr = wf + (r << 12);
        #pragma unroll
        for (int nt = 0; nt < 4; ++nt) {
            const f16* bp = wr + (nt * 16 + l15) * DD + lg * 8;
            f16x8 b0 = *(const f16x8*)bp;
            f16x8 b1 = *(const f16x8*)(bp + 32);
            q4[nt] = __builtin_amdgcn_mfma_f32_16x16x32_f16(u0, b0, q4[nt], 0, 0, 0);
            q4[nt] = __builtin_amdgcn_mfma_f32_16x16x32_f16(u1, b1, q4[nt], 0, 0, 0);
        }

        #pragma unroll
        for (int reg = 0; reg < 4; ++reg) {
            f16* qp = q_lds + (lg * 4 + reg) * QSTRIDE + r * 64 + l15;
            #pragma unroll
            for (int nt = 0; nt < 4; ++nt)
                qp[nt * 16] = (f16)q4[nt][reg];
        }
    }
    __syncthreads();

    // ---- Phase 2: node n0+w; group g (8 lanes) handles edges row0 + 8k + g ----
    int n = n0 + w;
    const f16* ql = q_lds + w * QSTRIDE;
    int row0 = rowptr[n], row1 = rowptr[n + 1];
    int deg = row1 - row0;
    int g  = l >> 3;       // group id 0..7
    int d8 = l & 7;        // element cluster: elems 8*d8 .. +7

    float zr = 0.f;
    float a[8] = {};

    int steps = (deg + 7) >> 3;
    for (int k = 0; k < steps; ++k) {
        int idx = row0 + (k << 3) + g;
        bool ok = idx < row1;
        int p = epack[ok ? idx : row0];
        int s = p & 0xffff, rr = p >> 16;
        f16x8 hv = *(const f16x8*)(hfin + ((size_t)s << 6) + (d8 << 3));
        f16x8 qv = *(const f16x8*)(ql + (rr << 6) + (d8 << 3));
        float dp = 0.f;
        #pragma unroll
        for (int j = 0; j < 4; ++j) {
            f16x2 ha = {hv[2 * j], hv[2 * j + 1]};
            f16x2 qa = {qv[2 * j], qv[2 * j + 1]};
            dp = dot2acc(ha, qa, dp);
        }
        dp = xor1_add(dp);                 // VALU DPP
        dp = xor2_add(dp);                 // VALU DPP
        dp += __shfl_xor(dp, 4, 64);       // DS
        float wg = ok ? __expf(dp) : 0.f;  // scores bounded; softmax shift-invariant
        zr += wg;
        #pragma unroll
        for (int j = 0; j < 8; ++j)
            a[j] = fmaf(wg, (float)hv[j], a[j]);
    }

    // merge the 8 group partial sums: xor8 on VALU (DPP), xor16/32 via shfl
    zr = xor8_add(zr);
    #pragma unroll
    for (int j = 0; j < 8; ++j) a[j] = xor8_add(a[j]);
    #pragma unroll
    for (int o = 16; o < 64; o <<= 1) {
        zr += __shfl_xor(zr, o, 64);
        #pragma unroll
        for (int j = 0; j < 8; ++j)
            a[j] += __shfl_xor(a[j], o, 64);
    }

    // g==0 lanes (d8 = 0..7) hold the full row; v1/v2 from the dense f16 h row
    if (g == 0) {
        float inv = (deg > 0) ? 1.f / zr : 0.f;
        f16x8 hrow = *(const f16x8*)(hfin + ((size_t)n << 6) + (d8 << 3));
        f16x8 v1v, v2v;
        #pragma unroll
        for (int j = 0; j < 8; ++j) {
            float h = (float)hrow[j];
            float nb = a[j] * inv;
            v1v[j] = (f16)(h + nb);
            v2v[j] = (f16)(h * nb);
        }
        *(f16x8*)(q_lds + w * QSTRIDE + (d8 << 3)) = v1v;
        *(f16x8*)(q_lds + w * QSTRIDE + 256 + (d8 << 3)) = v2v;
    }
    __syncthreads();

    // ---- Phase 3: epilogue OUT = leaky(V1@ra) + leaky(V2@rb), waves 0-3 ----
    if (w < 4) {
        const f16* v1p = q_lds + (size_t)l15 * QSTRIDE + lg * 8;
        f16x8 a10 = *(const f16x8*)v1p;
        f16x8 a11 = *(const f16x8*)(v1p + 32);
        const f16* v2p = v1p + 256;
        f16x8 a20 = *(const f16x8*)v2p;
        f16x8 a21 = *(const f16x8*)(v2p + 32);

        const f16* bra = rat + (w * 16 + l15) * 64 + lg * 8;   // B^T rows = ra cols
        f16x8 b10 = *(const f16x8*)bra;
        f16x8 b11 = *(const f16x8*)(bra + 32);
        const f16* brb = rbt + (w * 16 + l15) * 64 + lg * 8;
        f16x8 b20 = *(const f16x8*)brb;
        f16x8 b21 = *(const f16x8*)(brb + 32);

        f32x4 o1 = (f32x4){0.f, 0.f, 0.f, 0.f};
        f32x4 o2 = (f32x4){0.f, 0.f, 0.f, 0.f};
        o1 = __builtin_amdgcn_mfma_f32_16x16x32_f16(a10, b10, o1, 0, 0, 0);
        o1 = __builtin_amdgcn_mfma_f32_16x16x32_f16(a11, b11, o1, 0, 0, 0);
        o2 = __builtin_amdgcn_mfma_f32_16x16x32_f16(a20, b20, o2, 0, 0, 0);
        o2 = __builtin_amdgcn_mfma_f32_16x16x32_f16(a21, b21, o2, 0, 0, 0);

        int dp = w * 16 + l15;                   // output dim
        #pragma unroll
        for (int reg = 0; reg < 4; ++reg) {
            int node = n0 + lg * 4 + reg;        // C row = node
            float u1 = o1[reg], u2 = o2[reg];
            u1 = u1 > 0.f ? u1 : 0.01f * u1;
            u2 = u2 > 0.f ? u2 : 0.01f * u2;
            float v = u1 + u2;
            out[(size_t)node * OSTRIDE + off_out + dp] = v;
            hfout[(size_t)node * DD + dp] = (f16)v;
        }
    }
}

// ---------- launch ----------
extern "C" void kernel_launch(void* const* d_in, const int* in_sizes, int n_in,
                              void* d_out, int out_size, void* d_ws, size_t ws_size,
                              hipStream_t stream) {
    const int*   node_ids = (const int*)d_in[0];
    const int*   rel_ids  = (const int*)d_in[1];
    const int*   src      = (const int*)d_in[2];
    const int*   dst      = (const int*)d_in[3];
    const float* ent      = (const float*)d_in[4];
    const float* relE     = (const float*)d_in[5];
    const float* W[2]  = {(const float*)d_in[6], (const float*)d_in[7]};
    const float* ra[2] = {(const float*)d_in[8], (const float*)d_in[10]};
    const float* rb[2] = {(const float*)d_in[9], (const float*)d_in[11]};
    float* out = (float*)d_out;

    const size_t hf_bytes     = (size_t)NN * DD * sizeof(f16);         // 6.4 MB
    const size_t wf_bytes     = (size_t)NR * DD * DD * sizeof(f16);    // 128 KB
    const size_t rt_bytes     = (size_t)DD * DD * sizeof(f16);         // 8 KB
    const size_t epack_bytes  = (size_t)NE * sizeof(int);              // 3.2 MB
    const size_t rowptr_bytes = (size_t)(NN + 1) * sizeof(int);
    const size_t cnt_bytes    = (size_t)NN * sizeof(int);
    const int    NB_SCAN      = (NN + 255) / 256;   // 196
    const size_t bsum_bytes   = (size_t)256 * sizeof(int);

    char* p = (char*)d_ws;
    f16*   hf     = (f16*)p;   p += hf_bytes;
    f16*   hf2    = (f16*)p;   p += hf_bytes;   // ping-pong shadow
    f16*   wf     = (f16*)p;   p += wf_bytes;
    f16*   wtf    = (f16*)p;   p += wf_bytes;
    f16*   rat    = (f16*)p;   p += rt_bytes;
    f16*   rbt    = (f16*)p;   p += rt_bytes;
    int*   epack  = (int*)p;   p += epack_bytes;
    int*   rowptr = (int*)p;   p += rowptr_bytes;
    int*   cnt    = (int*)p;   p += cnt_bytes;
    int*   bsum   = (int*)p;   p += bsum_bytes;
    (void)ws_size;

    // ---- CSR build (shared by both layers) ----
    hipMemsetAsync(cnt, 0, cnt_bytes, stream);
    k_deg  <<<1024, 256, 0, stream>>>(dst, cnt);
    k_scan1<<<NB_SCAN, 256, 0, stream>>>(cnt, rowptr, bsum);
    k_scan2<<<1, 256, 0, stream>>>(bsum, NB_SCAN);
    k_scan3<<<NB_SCAN, 256, 0, stream>>>(rowptr, bsum, cnt);
    k_fill <<<1024, 256, 0, stream>>>(dst, src, rel_ids, cnt, epack);

    // ---- h0 ----
    k_copy_h0<<<(NN * DD + 255) / 256, 256, 0, stream>>>(node_ids, ent, out, hf);

    f16* hin  = hf;
    f16* hout = hf2;
    for (int L = 0; L < 2; ++L) {
        int off_in = L * DD;
        int off_out = (L + 1) * DD;

        k_prep  <<<(NR * DD * DD + 255) / 256, 256, 0, stream>>>(W[L], ra[L], rb[L],
                                                                 wf, wtf, rat, rbt);
        k_fused10<<<NN / 16, 1024, 0, stream>>>(hin, wf, wtf, rat, rbt, relE,
                                                rowptr, epack, out,
                                                off_in, off_out, hout);
        f16* tmp = hin; hin = hout; hout = tmp;
    }
}